// Round 2
// baseline (1953.570 us; speedup 1.0000x reference)
//
#include <hip/hip_runtime.h>
#include <hip/hip_bf16.h>
#include <stdint.h>
#include <stddef.h>

// ---------------- problem dims (fixed by setup_inputs) ----------------
#define M_DIM 8192
#define K_DIM 4096
#define N_DIM 16384

#define BM 128
#define BN 128
#define BK 32

typedef __attribute__((ext_vector_type(8))) short bf16x8;  // 8 bf16 = 4 VGPRs
typedef __attribute__((ext_vector_type(4))) float f32x4;
typedef __attribute__((ext_vector_type(4))) int   i32x4;

// fp32 -> bf16, round-to-nearest-even (inputs finite)
static __device__ __forceinline__ short f2bf(float f) {
    union { float f; uint32_t u; } v; v.f = f;
    uint32_t r = v.u + 0x7FFFu + ((v.u >> 16) & 1u);
    return (short)(r >> 16);
}

// FP4 E2M1 decode: low 3 bits magnitude code, bit 3 sign.
// mag table {0,0.5,1,1.5,2,3,4,6} == (e==0 ? 0.5*m : (2+m)*0.25*2^e)
static __device__ __forceinline__ float e2m1(int v) {
    int e = (v >> 1) & 3;
    int m = v & 1;
    float mag = (e == 0) ? 0.5f * (float)m
                         : (float)(2 + m) * 0.25f * (float)(1 << e);
    return (v & 8) ? -mag : mag;
}

// async global->LDS, 16 bytes per lane; LDS dest must be wave-uniform base
static __device__ __forceinline__ void gload16(short* lds, const short* g) {
    __builtin_amdgcn_global_load_lds(
        (const __attribute__((address_space(1))) void*)g,
        (__attribute__((address_space(3))) void*)lds,
        16, 0, 0);
}

// ---------------- kernel 1: x fp32 -> bf16 ----------------
__global__ void cast_x_kernel(const float* __restrict__ x, short* __restrict__ xb) {
    size_t i = (size_t)blockIdx.x * 256 + threadIdx.x;   // one short8 per thread
    const float4* s = reinterpret_cast<const float4*>(x);
    float4 a = s[2 * i];
    float4 b = s[2 * i + 1];
    bf16x8 o;
    o[0] = f2bf(a.x); o[1] = f2bf(a.y); o[2] = f2bf(a.z); o[3] = f2bf(a.w);
    o[4] = f2bf(b.x); o[5] = f2bf(b.y); o[6] = f2bf(b.z); o[7] = f2bf(b.w);
    reinterpret_cast<bf16x8*>(xb)[i] = o;
}

// ---------------- kernel 2: dequant w_q -> bf16 [N, K] ----------------
// one thread per inner block of 16 elements (= 8 packed bytes)
__global__ void dequant_w_kernel(const int* __restrict__ wq,
                                 const float* __restrict__ wos,
                                 const float* __restrict__ wis,
                                 short* __restrict__ wb) {
    int tid = blockIdx.x * 256 + threadIdx.x;    // N*(K/16) = 4,194,304 total
    int n   = tid >> 8;                          // K/16 = 256 inner blocks per row
    int blk = tid & 255;
    float scale = wis[(n << 8) | blk] * wos[(n << 5) | (blk >> 3)];
    const i32x4* q = reinterpret_cast<const i32x4*>(wq + ((size_t)n << 11) + (blk << 3));
    i32x4 q0 = q[0], q1 = q[1];
    bf16x8 o0, o1;
#pragma unroll
    for (int j = 0; j < 4; ++j) {
        int c = q0[j];
        o0[2 * j]     = f2bf(e2m1(c & 15) * scale);         // even in-feature
        o0[2 * j + 1] = f2bf(e2m1((c >> 4) & 15) * scale);  // odd in-feature
    }
#pragma unroll
    for (int j = 0; j < 4; ++j) {
        int c = q1[j];
        o1[2 * j]     = f2bf(e2m1(c & 15) * scale);
        o1[2 * j + 1] = f2bf(e2m1((c >> 4) & 15) * scale);
    }
    bf16x8* dst = reinterpret_cast<bf16x8*>(wb) + 2 * (size_t)tid;
    dst[0] = o0;
    dst[1] = o1;
}

// ---------------- kernel 3: C[M,N] = A[M,K] * B[N,K]^T, bf16 in / fp32 out --
// m97 structure: 128x128 tile, BK=32, 4 waves (2x2), 4x4 16x16x32 frags/wave,
// global_load_lds width-16 staging, 2 barriers per K-step.
// LDS bank-conflict fix (T2 / rule #21): XOR-swizzle the 16B slot within each
// 64B row: slot = kchunk ^ (row&3) ^ ((row>>2)&3). Applied on BOTH sides:
// read offsets use it, and the global SOURCE address is pre-swizzled so the
// linear global_load_lds write lands data where the swizzled read expects it.
__global__ __launch_bounds__(256)
void gemm_bt_kernel(const short* __restrict__ A,
                    const short* __restrict__ B,
                    float* __restrict__ C) {
    __shared__ short As[BM * BK];   // 8 KB, row-major [128][32], slot-swizzled
    __shared__ short Bs[BN * BK];   // 8 KB

    // bijective XCD swizzle (nwg = 8192, divisible by 8)
    int bid = blockIdx.x;
    int cpx = gridDim.x >> 3;
    int wg  = (bid & 7) * cpx + (bid >> 3);
    int bm  = (wg & 63) << 7;       // m-fast within an XCD chunk
    int bn  = (wg >> 6) << 7;

    int t    = threadIdx.x;
    int lane = t & 63;
    int wave = t >> 6;
    int wm   = (wave >> 1) << 6;    // wave 64x64 sub-tile
    int wn   = (wave & 1) << 6;
    int fr   = lane & 15;
    int fq   = lane >> 4;

    // staging: thread t fills LDS bytes [t*16, t*16+16) per 64-row issue
    // (row srow, slot t&3). Pre-swizzle the GLOBAL slot so LDS[row][slot]
    // holds global k-chunk (slot ^ c(row)).
    int srow = t >> 2;                                    // 0..63
    int gslot = (t & 3) ^ (srow & 3) ^ ((srow >> 2) & 3); // inverse (= same) swizzle
    int scol = gslot << 3;                                // shorts
    const short* Ag = A + (size_t)(bm + srow) * K_DIM + scol;
    const short* Bg = B + (size_t)(bn + srow) * K_DIM + scol;

    short* AsW = As + wave * 512;   // wave-uniform LDS base (1024 B / wave / issue)
    short* BsW = Bs + wave * 512;

    f32x4 acc[4][4] = {};

    const bf16x8* Af = reinterpret_cast<const bf16x8*>(As);
    const bf16x8* Bf = reinterpret_cast<const bf16x8*>(Bs);
    // fragment row = (multiple of 16) + fr, so row&15 == fr: the read-side
    // swizzled slot is constant per lane.
    int slot = fq ^ (fr & 3) ^ ((fr >> 2) & 3);
    int aoff[4], boff[4];
#pragma unroll
    for (int i = 0; i < 4; ++i) {
        aoff[i] = (wm + i * 16 + fr) * 4 + slot;   // bf16x8 index into As
        boff[i] = (wn + i * 16 + fr) * 4 + slot;
    }

    for (int k0 = 0; k0 < K_DIM; k0 += BK) {
        // stage A tile (2 issues of 64 rows) and B tile
        gload16(AsW,        Ag + k0);
        gload16(AsW + 2048, Ag + (size_t)64 * K_DIM + k0);
        gload16(BsW,        Bg + k0);
        gload16(BsW + 2048, Bg + (size_t)64 * K_DIM + k0);
        __syncthreads();   // drains vmcnt before barrier (compiler-emitted)

        bf16x8 a[4], b[4];
#pragma unroll
        for (int i = 0; i < 4; ++i) {
            a[i] = Af[aoff[i]];
            b[i] = Bf[boff[i]];
        }
#pragma unroll
        for (int mi = 0; mi < 4; ++mi)
#pragma unroll
            for (int ni = 0; ni < 4; ++ni)
                acc[mi][ni] = __builtin_amdgcn_mfma_f32_16x16x32_bf16(
                    a[mi], b[ni], acc[mi][ni], 0, 0, 0);
        __syncthreads();
    }

    // epilogue: C/D layout col = lane&15, row = (lane>>4)*4 + reg (m89/m91-verified)
#pragma unroll
    for (int mi = 0; mi < 4; ++mi) {
#pragma unroll
        for (int j = 0; j < 4; ++j) {
            size_t row = (size_t)(bm + wm + mi * 16 + fq * 4 + j);
            float* Crow = C + row * N_DIM + (bn + wn + fr);
#pragma unroll
            for (int ni = 0; ni < 4; ++ni)
                Crow[ni * 16] = acc[mi][ni][j];
        }
    }
}

// ---------------- launch ----------------
extern "C" void kernel_launch(void* const* d_in, const int* in_sizes, int n_in,
                              void* d_out, int out_size, void* d_ws, size_t ws_size,
                              hipStream_t stream) {
    const float* x   = (const float*)d_in[0];
    const int*   wq  = (const int*)d_in[1];
    const float* wos = (const float*)d_in[2];
    const float* wis = (const float*)d_in[3];
    // d_in[4] (w_t) unused: dequantizing packed codes is half the read traffic
    float* out = (float*)d_out;

    short* xb = (short*)d_ws;                                        // 64 MB
    short* wb = (short*)((char*)d_ws + (size_t)M_DIM * K_DIM * 2);   // 128 MB

    cast_x_kernel<<<(M_DIM * (size_t)K_DIM / 8) / 256, 256, 0, stream>>>(x, xb);
    dequant_w_kernel<<<(N_DIM * (size_t)K_DIM / 16) / 256, 256, 0, stream>>>(wq, wos, wis, wb);
    gemm_bt_kernel<<<(M_DIM / BM) * (N_DIM / BN), 256, 0, stream>>>(xb, wb, out);
}

// Round 3
// 1823.353 us; speedup vs baseline: 1.0714x; 1.0714x over previous
//
#include <hip/hip_runtime.h>
#include <hip/hip_bf16.h>
#include <stdint.h>
#include <stddef.h>

// ---------------- problem dims (fixed by setup_inputs) ----------------
#define M_DIM 8192
#define K_DIM 4096
#define N_DIM 16384

#define BM 128
#define BN 128
#define BK 32

typedef __attribute__((ext_vector_type(8))) short bf16x8;  // 8 bf16 = 4 VGPRs
typedef __attribute__((ext_vector_type(4))) float f32x4;
typedef __attribute__((ext_vector_type(4))) int   i32x4;

// fp32 -> bf16, round-to-nearest-even (inputs finite)
static __device__ __forceinline__ short f2bf(float f) {
    union { float f; uint32_t u; } v; v.f = f;
    uint32_t r = v.u + 0x7FFFu + ((v.u >> 16) & 1u);
    return (short)(r >> 16);
}

// FP4 E2M1 decode: low 3 bits magnitude code, bit 3 sign.
static __device__ __forceinline__ float e2m1(int v) {
    int e = (v >> 1) & 3;
    int m = v & 1;
    float mag = (e == 0) ? 0.5f * (float)m
                         : (float)(2 + m) * 0.25f * (float)(1 << e);
    return (v & 8) ? -mag : mag;
}

// async global->LDS, 16 bytes per lane; LDS dest must be wave-uniform base
static __device__ __forceinline__ void gload16(short* lds, const short* g) {
    __builtin_amdgcn_global_load_lds(
        (const __attribute__((address_space(1))) void*)g,
        (__attribute__((address_space(3))) void*)lds,
        16, 0, 0);
}

// ---------------- kernel 1: x fp32 -> bf16 ----------------
__global__ void cast_x_kernel(const float* __restrict__ x, short* __restrict__ xb) {
    size_t i = (size_t)blockIdx.x * 256 + threadIdx.x;   // one short8 per thread
    const float4* s = reinterpret_cast<const float4*>(x);
    float4 a = s[2 * i];
    float4 b = s[2 * i + 1];
    bf16x8 o;
    o[0] = f2bf(a.x); o[1] = f2bf(a.y); o[2] = f2bf(a.z); o[3] = f2bf(a.w);
    o[4] = f2bf(b.x); o[5] = f2bf(b.y); o[6] = f2bf(b.z); o[7] = f2bf(b.w);
    reinterpret_cast<bf16x8*>(xb)[i] = o;
}

// ---------------- kernel 2: dequant w_q -> bf16 [N, K] ----------------
__global__ void dequant_w_kernel(const int* __restrict__ wq,
                                 const float* __restrict__ wos,
                                 const float* __restrict__ wis,
                                 short* __restrict__ wb) {
    int tid = blockIdx.x * 256 + threadIdx.x;    // N*(K/16) = 4,194,304 total
    int n   = tid >> 8;                          // K/16 = 256 inner blocks per row
    int blk = tid & 255;
    float scale = wis[(n << 8) | blk] * wos[(n << 5) | (blk >> 3)];
    const i32x4* q = reinterpret_cast<const i32x4*>(wq + ((size_t)n << 11) + (blk << 3));
    i32x4 q0 = q[0], q1 = q[1];
    bf16x8 o0, o1;
#pragma unroll
    for (int j = 0; j < 4; ++j) {
        int c = q0[j];
        o0[2 * j]     = f2bf(e2m1(c & 15) * scale);         // even in-feature
        o0[2 * j + 1] = f2bf(e2m1((c >> 4) & 15) * scale);  // odd in-feature
    }
#pragma unroll
    for (int j = 0; j < 4; ++j) {
        int c = q1[j];
        o1[2 * j]     = f2bf(e2m1(c & 15) * scale);
        o1[2 * j + 1] = f2bf(e2m1((c >> 4) & 15) * scale);
    }
    bf16x8* dst = reinterpret_cast<bf16x8*>(wb) + 2 * (size_t)tid;
    dst[0] = o0;
    dst[1] = o1;
}

// ---------------- kernel 3: C[M,N] = A[M,K] * B[N,K]^T, bf16 in / fp32 out --
// m97 structure (128x128 tile, BK=32, 4 waves, global_load_lds width-16).
// NOTE (R2 finding): SQ_LDS_BANK_CONFLICT for this kernel is exactly
// 4 cycles per ds_read_b128 (verified vs m98: same per-read rate) —
// inherent b128 cost, NOT a fixable conflict. Ignore that counter here.
//
// R3 change: hierarchical block rasterization for L2/L3 locality.
//   level 0: bijective XCD chunking (8 chunks of 1024 blocks).
//   level 1: each XCD owns one N-stripe (2048 cols) = 4 super-tiles of
//            16m x 16n tiles (2048x2048 output), stacked over M.
//   level 2: n-fast within a super-tile -> ~64 concurrent blocks/XCD touch
//            4 A-panels (4 MB, fits 4 MB per-XCD L2) x 16 B-panels (L3).
__global__ __launch_bounds__(256)
void gemm_bt_kernel(const short* __restrict__ A,
                    const short* __restrict__ B,
                    float* __restrict__ C) {
    __shared__ short As[BM * BK];   // 8 KB, row-major [128][32], slot-swizzled
    __shared__ short Bs[BN * BK];   // 8 KB

    // ---- block rasterization ----
    int bid = blockIdx.x;                        // 0..8191
    int wg  = (bid & 7) * 1024 + (bid >> 3);     // XCD-contiguous chunks
    int s     = wg >> 8;                         // super-tile 0..31
    int inner = wg & 255;                        // 0..255 within super
    int sm = s & 3;                              // 4 super-rows (M)
    int sn = s >> 2;                             // 8 super-cols (N) = per-XCD stripe
    int im  = inner >> 4;                        // slow: 16 m-tiles
    int in_ = inner & 15;                        // fast: 16 n-tiles
    int bm = (sm * 16 + im) << 7;                // 0..8191
    int bn = (sn * 16 + in_) << 7;               // 0..16383

    int t    = threadIdx.x;
    int lane = t & 63;
    int wave = t >> 6;
    int wm   = (wave >> 1) << 6;    // wave 64x64 sub-tile
    int wn   = (wave & 1) << 6;
    int fr   = lane & 15;
    int fq   = lane >> 4;

    // staging: thread t fills LDS bytes [t*16, t*16+16) per 64-row issue
    int srow = t >> 2;                                    // 0..63
    int gslot = (t & 3) ^ (srow & 3) ^ ((srow >> 2) & 3); // involution swizzle
    int scol = gslot << 3;                                // shorts
    const short* Ag = A + (size_t)(bm + srow) * K_DIM + scol;
    const short* Bg = B + (size_t)(bn + srow) * K_DIM + scol;

    short* AsW = As + wave * 512;   // wave-uniform LDS base (1024 B / wave / issue)
    short* BsW = Bs + wave * 512;

    f32x4 acc[4][4] = {};

    const bf16x8* Af = reinterpret_cast<const bf16x8*>(As);
    const bf16x8* Bf = reinterpret_cast<const bf16x8*>(Bs);
    int slot = fq ^ (fr & 3) ^ ((fr >> 2) & 3);   // read-side of the involution
    int aoff[4], boff[4];
#pragma unroll
    for (int i = 0; i < 4; ++i) {
        aoff[i] = (wm + i * 16 + fr) * 4 + slot;   // bf16x8 index into As
        boff[i] = (wn + i * 16 + fr) * 4 + slot;
    }

    for (int k0 = 0; k0 < K_DIM; k0 += BK) {
        gload16(AsW,        Ag + k0);
        gload16(AsW + 2048, Ag + (size_t)64 * K_DIM + k0);
        gload16(BsW,        Bg + k0);
        gload16(BsW + 2048, Bg + (size_t)64 * K_DIM + k0);
        __syncthreads();

        bf16x8 a[4], b[4];
#pragma unroll
        for (int i = 0; i < 4; ++i) {
            a[i] = Af[aoff[i]];
            b[i] = Bf[boff[i]];
        }
#pragma unroll
        for (int mi = 0; mi < 4; ++mi)
#pragma unroll
            for (int ni = 0; ni < 4; ++ni)
                acc[mi][ni] = __builtin_amdgcn_mfma_f32_16x16x32_bf16(
                    a[mi], b[ni], acc[mi][ni], 0, 0, 0);
        __syncthreads();
    }

    // epilogue: C/D layout col = lane&15, row = (lane>>4)*4 + reg
#pragma unroll
    for (int mi = 0; mi < 4; ++mi) {
#pragma unroll
        for (int j = 0; j < 4; ++j) {
            size_t row = (size_t)(bm + wm + mi * 16 + fq * 4 + j);
            float* Crow = C + row * N_DIM + (bn + wn + fr);
#pragma unroll
            for (int ni = 0; ni < 4; ++ni)
                Crow[ni * 16] = acc[mi][ni][j];
        }
    }
}

// ---------------- launch ----------------
extern "C" void kernel_launch(void* const* d_in, const int* in_sizes, int n_in,
                              void* d_out, int out_size, void* d_ws, size_t ws_size,
                              hipStream_t stream) {
    const float* x   = (const float*)d_in[0];
    const int*   wq  = (const int*)d_in[1];
    const float* wos = (const float*)d_in[2];
    const float* wis = (const float*)d_in[3];
    float* out = (float*)d_out;

    short* xb = (short*)d_ws;                                        // 64 MB
    short* wb = (short*)((char*)d_ws + (size_t)M_DIM * K_DIM * 2);   // 128 MB

    cast_x_kernel<<<(M_DIM * (size_t)K_DIM / 8) / 256, 256, 0, stream>>>(x, xb);
    dequant_w_kernel<<<(N_DIM * (size_t)K_DIM / 16) / 256, 256, 0, stream>>>(wq, wos, wis, wb);
    gemm_bt_kernel<<<(M_DIM / BM) * (N_DIM / BN), 256, 0, stream>>>(xb, wb, out);
}

// Round 4
// 1399.982 us; speedup vs baseline: 1.3954x; 1.3024x over previous
//
#include <hip/hip_runtime.h>
#include <hip/hip_bf16.h>
#include <stdint.h>
#include <stddef.h>

// ---------------- problem dims (fixed by setup_inputs) ----------------
#define M_DIM 8192
#define K_DIM 4096
#define N_DIM 16384

#define BM 256
#define BN 256
#define BK 32
#define NBUF 4                  // LDS ring depth (prefetch distance 3)
#define KSTEPS (K_DIM / BK)     // 128
#define TILE_SH (BM * BK)       // 8192 shorts = 16 KB per matrix per buffer

typedef __attribute__((ext_vector_type(8))) short bf16x8;  // 8 bf16 = 4 VGPRs
typedef __attribute__((ext_vector_type(4))) float f32x4;
typedef __attribute__((ext_vector_type(4))) int   i32x4;

// fp32 -> bf16, round-to-nearest-even (inputs finite)
static __device__ __forceinline__ short f2bf(float f) {
    union { float f; uint32_t u; } v; v.f = f;
    uint32_t r = v.u + 0x7FFFu + ((v.u >> 16) & 1u);
    return (short)(r >> 16);
}

// FP4 E2M1 decode: low 3 bits magnitude code, bit 3 sign.
static __device__ __forceinline__ float e2m1(int v) {
    int e = (v >> 1) & 3;
    int m = v & 1;
    float mag = (e == 0) ? 0.5f * (float)m
                         : (float)(2 + m) * 0.25f * (float)(1 << e);
    return (v & 8) ? -mag : mag;
}

// async global->LDS, 16 bytes per lane; LDS dest is wave-uniform base + lane*16
static __device__ __forceinline__ void gload16(short* lds, const short* g) {
    __builtin_amdgcn_global_load_lds(
        (const __attribute__((address_space(1))) void*)g,
        (__attribute__((address_space(3))) void*)lds,
        16, 0, 0);
}

// ---------------- kernel 1: x fp32 -> bf16 ----------------
__global__ void cast_x_kernel(const float* __restrict__ x, short* __restrict__ xb) {
    size_t i = (size_t)blockIdx.x * 256 + threadIdx.x;   // one short8 per thread
    const float4* s = reinterpret_cast<const float4*>(x);
    float4 a = s[2 * i];
    float4 b = s[2 * i + 1];
    bf16x8 o;
    o[0] = f2bf(a.x); o[1] = f2bf(a.y); o[2] = f2bf(a.z); o[3] = f2bf(a.w);
    o[4] = f2bf(b.x); o[5] = f2bf(b.y); o[6] = f2bf(b.z); o[7] = f2bf(b.w);
    reinterpret_cast<bf16x8*>(xb)[i] = o;
}

// ---------------- kernel 2: dequant w_q -> bf16 [N, K] ----------------
__global__ void dequant_w_kernel(const int* __restrict__ wq,
                                 const float* __restrict__ wos,
                                 const float* __restrict__ wis,
                                 short* __restrict__ wb) {
    int tid = blockIdx.x * 256 + threadIdx.x;    // N*(K/16) = 4,194,304 total
    int n   = tid >> 8;                          // K/16 = 256 inner blocks per row
    int blk = tid & 255;
    float scale = wis[(n << 8) | blk] * wos[(n << 5) | (blk >> 3)];
    const i32x4* q = reinterpret_cast<const i32x4*>(wq + ((size_t)n << 11) + (blk << 3));
    i32x4 q0 = q[0], q1 = q[1];
    bf16x8 o0, o1;
#pragma unroll
    for (int j = 0; j < 4; ++j) {
        int c = q0[j];
        o0[2 * j]     = f2bf(e2m1(c & 15) * scale);         // even in-feature
        o0[2 * j + 1] = f2bf(e2m1((c >> 4) & 15) * scale);  // odd in-feature
    }
#pragma unroll
    for (int j = 0; j < 4; ++j) {
        int c = q1[j];
        o1[2 * j]     = f2bf(e2m1(c & 15) * scale);
        o1[2 * j + 1] = f2bf(e2m1((c >> 4) & 15) * scale);
    }
    bf16x8* dst = reinterpret_cast<bf16x8*>(wb) + 2 * (size_t)tid;
    dst[0] = o0;
    dst[1] = o1;
}

// ---------------- kernel 3: C[M,N] = A[M,K] * B[N,K]^T, bf16 in / fp32 out --
// 256x256 tile, BK=32, 512 threads (8 waves, 2M x 4N; 128x64 per wave).
// T3+T4: 4-buffer LDS ring, prefetch distance 3, counted vmcnt(12) -- never
// drained to 0 in the main loop; raw s_barrier pairs (no __syncthreads drain).
// Safety: buffer staged at step t is buf[(t+3)%4], last read at step t-1 and
// protected by t-1's closing barrier -> no landing race.
// T5: setprio(1) around each 16-MFMA cluster.
// Both-sides 16B-slot XOR swizzle (involution): LDS[row][s] holds global
// k-slot s ^ ((row>>1)&3); read slot = fq ^ ((fr>>1)&3).
__global__ __launch_bounds__(512)
void gemm_bt_kernel(const short* __restrict__ A,
                    const short* __restrict__ B,
                    float* __restrict__ C) {
    __shared__ __align__(16) short As[NBUF * TILE_SH];   // 64 KB
    __shared__ __align__(16) short Bs[NBUF * TILE_SH];   // 64 KB

    // raster: 2048 blocks = 32 m-tiles x 64 n-tiles; each XCD owns an 8-wide
    // n-stripe, n-fast within -> active k-slice set ~384 KB (fits 4MB L2).
    int bid = blockIdx.x;
    int xcd = bid & 7;
    int idx = bid >> 3;          // 0..255
    int im  = idx >> 3;          // 0..31
    int in8 = idx & 7;           // 0..7
    int bm  = im << 8;
    int bn  = ((xcd << 3) + in8) << 8;

    int t    = threadIdx.x;
    int lane = t & 63;
    int w    = t >> 6;           // wave 0..7
    int wm   = w >> 2;           // 0..1
    int wn   = w & 3;            // 0..3
    int fr   = lane & 15;
    int fq   = lane >> 4;
    int w512 = w << 9;           // wave-uniform LDS stage base (shorts)

    // staging: thread t covers row (t>>2) (+128 for 2nd load), 16B slot t&3.
    // source k-slot pre-swizzled: gslot = (t&3) ^ ((row>>1)&3) = (t&3)^((t>>3)&3)
    int gcol = (((t & 3) ^ ((t >> 3) & 3)) << 3);        // shorts
    const short* AgB = A + (size_t)(bm + (t >> 2)) * K_DIM + gcol;
    const short* BgB = B + (size_t)(bn + (t >> 2)) * K_DIM + gcol;

    // fragment read offsets (bf16x8 units within one buffer)
    int slot = fq ^ ((fr >> 1) & 3);
    int aoff[8], boff[4];
#pragma unroll
    for (int mi = 0; mi < 8; ++mi)
        aoff[mi] = ((wm << 7) + mi * 16 + fr) * 4 + slot;
#pragma unroll
    for (int ni = 0; ni < 4; ++ni)
        boff[ni] = ((wn << 6) + ni * 16 + fr) * 4 + slot;

    f32x4 acc[8][4] = {};

#define STAGE(buf, kidx)                                                      \
    do {                                                                      \
        int _k0 = (kidx) << 5;  /* shorts */                                  \
        int _ab = (buf) * TILE_SH;                                            \
        gload16(As + _ab + w512,        AgB + _k0);                           \
        gload16(As + _ab + 4096 + w512, AgB + (size_t)128 * K_DIM + _k0);     \
        gload16(Bs + _ab + w512,        BgB + _k0);                           \
        gload16(Bs + _ab + 4096 + w512, BgB + (size_t)128 * K_DIM + _k0);     \
    } while (0)

    // prologue: 3 K-steps in flight (12 loads)
    STAGE(0, 0);
    STAGE(1, 1);
    STAGE(2, 2);

    for (int tt = 0; tt < KSTEPS; ++tt) {
        // issue prefetch for step tt+3 (wrap: restage early k-slices into
        // buffers that are never read again -- harmless, keeps vmcnt uniform)
        int sidx = tt + 3;
        if (sidx >= KSTEPS) sidx -= KSTEPS;
        STAGE(sidx & 3, sidx);

        // wait for step tt's 4 loads (12 newer stay in flight), then sync
        asm volatile("s_waitcnt vmcnt(12)" ::: "memory");
        __builtin_amdgcn_s_barrier();

        const bf16x8* Af = reinterpret_cast<const bf16x8*>(As + (tt & 3) * TILE_SH);
        const bf16x8* Bf = reinterpret_cast<const bf16x8*>(Bs + (tt & 3) * TILE_SH);

        bf16x8 bv[4], av0[4], av1[4];
#pragma unroll
        for (int ni = 0; ni < 4; ++ni) bv[ni] = Bf[boff[ni]];
#pragma unroll
        for (int mi = 0; mi < 4; ++mi) av0[mi] = Af[aoff[mi]];

        __builtin_amdgcn_s_setprio(1);
#pragma unroll
        for (int mi = 0; mi < 4; ++mi)
#pragma unroll
            for (int ni = 0; ni < 4; ++ni)
                acc[mi][ni] = __builtin_amdgcn_mfma_f32_16x16x32_bf16(
                    av0[mi], bv[ni], acc[mi][ni], 0, 0, 0);
        __builtin_amdgcn_s_setprio(0);

#pragma unroll
        for (int mi = 0; mi < 4; ++mi) av1[mi] = Af[aoff[mi + 4]];

        __builtin_amdgcn_s_setprio(1);
#pragma unroll
        for (int mi = 0; mi < 4; ++mi)
#pragma unroll
            for (int ni = 0; ni < 4; ++ni)
                acc[mi + 4][ni] = __builtin_amdgcn_mfma_f32_16x16x32_bf16(
                    av1[mi], bv[ni], acc[mi + 4][ni], 0, 0, 0);
        __builtin_amdgcn_s_setprio(0);

        // all reads of buf[tt&3] done -> next iteration may overwrite it
        __builtin_amdgcn_s_barrier();
    }
#undef STAGE

    // epilogue: C/D layout col = lane&15, row = (lane>>4)*4 + reg
#pragma unroll
    for (int mi = 0; mi < 8; ++mi) {
#pragma unroll
        for (int j = 0; j < 4; ++j) {
            size_t row = (size_t)(bm + (wm << 7) + mi * 16 + fq * 4 + j);
            float* Crow = C + row * N_DIM + (bn + (wn << 6) + fr);
#pragma unroll
            for (int ni = 0; ni < 4; ++ni)
                Crow[ni * 16] = acc[mi][ni][j];
        }
    }
}

// ---------------- launch ----------------
extern "C" void kernel_launch(void* const* d_in, const int* in_sizes, int n_in,
                              void* d_out, int out_size, void* d_ws, size_t ws_size,
                              hipStream_t stream) {
    const float* x   = (const float*)d_in[0];
    const int*   wq  = (const int*)d_in[1];
    const float* wos = (const float*)d_in[2];
    const float* wis = (const float*)d_in[3];
    float* out = (float*)d_out;

    short* xb = (short*)d_ws;                                        // 64 MB
    short* wb = (short*)((char*)d_ws + (size_t)M_DIM * K_DIM * 2);   // 128 MB

    cast_x_kernel<<<(M_DIM * (size_t)K_DIM / 8) / 256, 256, 0, stream>>>(x, xb);
    dequant_w_kernel<<<(N_DIM * (size_t)K_DIM / 16) / 256, 256, 0, stream>>>(wq, wos, wis, wb);
    gemm_bt_kernel<<<(M_DIM / BM) * (N_DIM / BN), 512, 0, stream>>>(xb, wb, out);
}

// Round 5
// 1359.169 us; speedup vs baseline: 1.4373x; 1.0300x over previous
//
#include <hip/hip_runtime.h>
#include <hip/hip_bf16.h>
#include <stdint.h>
#include <stddef.h>

// ---------------- problem dims (fixed by setup_inputs) ----------------
#define M_DIM 8192
#define K_DIM 4096
#define N_DIM 16384

#define BM 256
#define BN 256
#define BK 32
#define NBUF 4                  // LDS ring depth (prefetch distance 3)
#define KSTEPS (K_DIM / BK)     // 128
#define TILE_SH (BM * BK)       // 8192 shorts = 16 KB per matrix per buffer

typedef __attribute__((ext_vector_type(8))) short bf16x8;  // 8 bf16 = 4 VGPRs
typedef __attribute__((ext_vector_type(4))) float f32x4;
typedef __attribute__((ext_vector_type(4))) int   i32x4;

// fp32 -> bf16, round-to-nearest-even (inputs finite)
static __device__ __forceinline__ short f2bf(float f) {
    union { float f; uint32_t u; } v; v.f = f;
    uint32_t r = v.u + 0x7FFFu + ((v.u >> 16) & 1u);
    return (short)(r >> 16);
}

// FP4 E2M1 decode: low 3 bits magnitude code, bit 3 sign.
static __device__ __forceinline__ float e2m1(int v) {
    int e = (v >> 1) & 3;
    int m = v & 1;
    float mag = (e == 0) ? 0.5f * (float)m
                         : (float)(2 + m) * 0.25f * (float)(1 << e);
    return (v & 8) ? -mag : mag;
}

// async global->LDS, 16 bytes per lane; LDS dest is wave-uniform base + lane*16
static __device__ __forceinline__ void gload16(short* lds, const short* g) {
    __builtin_amdgcn_global_load_lds(
        (const __attribute__((address_space(1))) void*)g,
        (__attribute__((address_space(3))) void*)lds,
        16, 0, 0);
}

// ---------------- kernel 1: x fp32 -> bf16 ----------------
__global__ void cast_x_kernel(const float* __restrict__ x, short* __restrict__ xb) {
    size_t i = (size_t)blockIdx.x * 256 + threadIdx.x;   // one short8 per thread
    const float4* s = reinterpret_cast<const float4*>(x);
    float4 a = s[2 * i];
    float4 b = s[2 * i + 1];
    bf16x8 o;
    o[0] = f2bf(a.x); o[1] = f2bf(a.y); o[2] = f2bf(a.z); o[3] = f2bf(a.w);
    o[4] = f2bf(b.x); o[5] = f2bf(b.y); o[6] = f2bf(b.z); o[7] = f2bf(b.w);
    reinterpret_cast<bf16x8*>(xb)[i] = o;
}

// ---------------- kernel 2: dequant w_q -> bf16 [N, K] ----------------
__global__ void dequant_w_kernel(const int* __restrict__ wq,
                                 const float* __restrict__ wos,
                                 const float* __restrict__ wis,
                                 short* __restrict__ wb) {
    int tid = blockIdx.x * 256 + threadIdx.x;    // N*(K/16) = 4,194,304 total
    int n   = tid >> 8;                          // K/16 = 256 inner blocks per row
    int blk = tid & 255;
    float scale = wis[(n << 8) | blk] * wos[(n << 5) | (blk >> 3)];
    const i32x4* q = reinterpret_cast<const i32x4*>(wq + ((size_t)n << 11) + (blk << 3));
    i32x4 q0 = q[0], q1 = q[1];
    bf16x8 o0, o1;
#pragma unroll
    for (int j = 0; j < 4; ++j) {
        int c = q0[j];
        o0[2 * j]     = f2bf(e2m1(c & 15) * scale);         // even in-feature
        o0[2 * j + 1] = f2bf(e2m1((c >> 4) & 15) * scale);  // odd in-feature
    }
#pragma unroll
    for (int j = 0; j < 4; ++j) {
        int c = q1[j];
        o1[2 * j]     = f2bf(e2m1(c & 15) * scale);
        o1[2 * j + 1] = f2bf(e2m1((c >> 4) & 15) * scale);
    }
    bf16x8* dst = reinterpret_cast<bf16x8*>(wb) + 2 * (size_t)tid;
    dst[0] = o0;
    dst[1] = o1;
}

// ---------------- kernel 3: C[M,N] = A[M,K] * B[N,K]^T, bf16 in / fp32 out --
// 256x256 tile, BK=32, 512 threads (8 waves, 2M x 4N; 128x64 per wave).
// R4 base: 4-buffer LDS ring, prefetch distance 3, counted vmcnt (never 0
// in-loop), raw s_barrier pairs, setprio around MFMA, conflict-free swizzle
// (verified: SQ_LDS_BANK_CONFLICT == 0).
// R5 change: ONE-STEP REGISTER READ-AHEAD. At step t (after vmcnt(8)+barrier,
// which guarantees STAGE(t+1) landed: outstanding = stages t+1,t+2,t+3 = 12,
// wait to 8), issue ds_reads of step t+1's bv/av0 frags from buf[(t+1)&3];
// the 32 MFMAs of step t consume registers read at step t-1 -> DS pipe drains
// UNDER the MFMA cluster instead of serializing before it. av1 stays in-step
// (hidden under MFMA cluster 1). Ping-pong banks via unroll-by-2 (static
// indexing, rule #20). Wrap-around reads at t=KSTEPS-1 are dead (unused, no
// fault). Frags 80 VGPR + acc 128 AGPR ~= 235 regs -> keeps 2 waves/SIMD.
__global__ __launch_bounds__(512)
void gemm_bt_kernel(const short* __restrict__ A,
                    const short* __restrict__ B,
                    float* __restrict__ C) {
    __shared__ __align__(16) short As[NBUF * TILE_SH];   // 64 KB
    __shared__ __align__(16) short Bs[NBUF * TILE_SH];   // 64 KB

    // raster: 2048 blocks = 32 m-tiles x 64 n-tiles; each XCD owns an 8-wide
    // n-stripe, n-fast within -> active k-slice set ~384 KB (fits 4MB L2).
    int bid = blockIdx.x;
    int xcd = bid & 7;
    int idx = bid >> 3;          // 0..255
    int im  = idx >> 3;          // 0..31
    int in8 = idx & 7;           // 0..7
    int bm  = im << 8;
    int bn  = ((xcd << 3) + in8) << 8;

    int t    = threadIdx.x;
    int lane = t & 63;
    int w    = t >> 6;           // wave 0..7
    int wm   = w >> 2;           // 0..1
    int wn   = w & 3;            // 0..3
    int fr   = lane & 15;
    int fq   = lane >> 4;
    int w512 = w << 9;           // wave-uniform LDS stage base (shorts)

    // staging: thread t covers row (t>>2) (+128 for 2nd load), 16B slot t&3.
    // source k-slot pre-swizzled: gslot = (t&3) ^ ((row>>1)&3) = (t&3)^((t>>3)&3)
    int gcol = (((t & 3) ^ ((t >> 3) & 3)) << 3);        // shorts
    const short* AgB = A + (size_t)(bm + (t >> 2)) * K_DIM + gcol;
    const short* BgB = B + (size_t)(bn + (t >> 2)) * K_DIM + gcol;

    // fragment read offsets (bf16x8 units within one buffer)
    int slot = fq ^ ((fr >> 1) & 3);
    int aoff[8], boff[4];
#pragma unroll
    for (int mi = 0; mi < 8; ++mi)
        aoff[mi] = ((wm << 7) + mi * 16 + fr) * 4 + slot;
#pragma unroll
    for (int ni = 0; ni < 4; ++ni)
        boff[ni] = ((wn << 6) + ni * 16 + fr) * 4 + slot;

    f32x4 acc[8][4] = {};

#define STAGE(buf, kidx)                                                      \
    do {                                                                      \
        int _k0 = (kidx) << 5;  /* shorts */                                  \
        int _ab = (buf) * TILE_SH;                                            \
        gload16(As + _ab + w512,        AgB + _k0);                           \
        gload16(As + _ab + 4096 + w512, AgB + (size_t)128 * K_DIM + _k0);     \
        gload16(Bs + _ab + w512,        BgB + _k0);                           \
        gload16(Bs + _ab + 4096 + w512, BgB + (size_t)128 * K_DIM + _k0);     \
    } while (0)

    bf16x8 bvP[4], a0P[4];   // ping bank
    bf16x8 bvQ[4], a0Q[4];   // pong bank
    bf16x8 av1[4];

    // prologue: 3 K-steps in flight, then load frags(0) into ping
    STAGE(0, 0);
    STAGE(1, 1);
    STAGE(2, 2);
    asm volatile("s_waitcnt vmcnt(8)" ::: "memory");   // STAGE(0) landed
    __builtin_amdgcn_s_barrier();
    {
        const bf16x8* Af = reinterpret_cast<const bf16x8*>(As);
        const bf16x8* Bf = reinterpret_cast<const bf16x8*>(Bs);
#pragma unroll
        for (int ni = 0; ni < 4; ++ni) bvP[ni] = Bf[boff[ni]];
#pragma unroll
        for (int mi = 0; mi < 4; ++mi) a0P[mi] = Af[aoff[mi]];
    }

    // one K-step: MFMA on bank C (frags of step tt), prefetch bank N (tt+1)
#define STEP(tt, bvC, a0C, bvN, a0N)                                          \
    do {                                                                      \
        int sidx = (tt) + 3;                                                  \
        if (sidx >= KSTEPS) sidx -= KSTEPS;                                   \
        STAGE(sidx & 3, sidx);                                                \
        asm volatile("s_waitcnt vmcnt(8)" ::: "memory"); /* STAGE(tt+1) in */ \
        __builtin_amdgcn_s_barrier();                                         \
        const bf16x8* AfN = reinterpret_cast<const bf16x8*>(As + (((tt) + 1) & 3) * TILE_SH); \
        const bf16x8* BfN = reinterpret_cast<const bf16x8*>(Bs + (((tt) + 1) & 3) * TILE_SH); \
        const bf16x8* AfC = reinterpret_cast<const bf16x8*>(As + ((tt) & 3) * TILE_SH);       \
        _Pragma("unroll")                                                     \
        for (int ni = 0; ni < 4; ++ni) bvN[ni] = BfN[boff[ni]];               \
        _Pragma("unroll")                                                     \
        for (int mi = 0; mi < 4; ++mi) a0N[mi] = AfN[aoff[mi]];               \
        _Pragma("unroll")                                                     \
        for (int mi = 0; mi < 4; ++mi) av1[mi] = AfC[aoff[mi + 4]];           \
        __builtin_amdgcn_s_setprio(1);                                        \
        _Pragma("unroll")                                                     \
        for (int mi = 0; mi < 4; ++mi)                                        \
            _Pragma("unroll")                                                 \
            for (int ni = 0; ni < 4; ++ni)                                    \
                acc[mi][ni] = __builtin_amdgcn_mfma_f32_16x16x32_bf16(        \
                    a0C[mi], bvC[ni], acc[mi][ni], 0, 0, 0);                  \
        _Pragma("unroll")                                                     \
        for (int mi = 0; mi < 4; ++mi)                                        \
            _Pragma("unroll")                                                 \
            for (int ni = 0; ni < 4; ++ni)                                    \
                acc[mi + 4][ni] = __builtin_amdgcn_mfma_f32_16x16x32_bf16(    \
                    av1[mi], bvC[ni], acc[mi + 4][ni], 0, 0, 0);              \
        __builtin_amdgcn_s_setprio(0);                                        \
        __builtin_amdgcn_s_barrier();                                         \
    } while (0)

    for (int tt = 0; tt < KSTEPS; tt += 2) {
        STEP(tt,     bvP, a0P, bvQ, a0Q);
        STEP(tt + 1, bvQ, a0Q, bvP, a0P);
    }
#undef STEP
#undef STAGE

    // epilogue: C/D layout col = lane&15, row = (lane>>4)*4 + reg
#pragma unroll
    for (int mi = 0; mi < 8; ++mi) {
#pragma unroll
        for (int j = 0; j < 4; ++j) {
            size_t row = (size_t)(bm + (wm << 7) + mi * 16 + fq * 4 + j);
            float* Crow = C + row * N_DIM + (bn + (wn << 6) + fr);
#pragma unroll
            for (int ni = 0; ni < 4; ++ni)
                Crow[ni * 16] = acc[mi][ni][j];
        }
    }
}

// ---------------- launch ----------------
extern "C" void kernel_launch(void* const* d_in, const int* in_sizes, int n_in,
                              void* d_out, int out_size, void* d_ws, size_t ws_size,
                              hipStream_t stream) {
    const float* x   = (const float*)d_in[0];
    const int*   wq  = (const int*)d_in[1];
    const float* wos = (const float*)d_in[2];
    const float* wis = (const float*)d_in[3];
    float* out = (float*)d_out;

    short* xb = (short*)d_ws;                                        // 64 MB
    short* wb = (short*)((char*)d_ws + (size_t)M_DIM * K_DIM * 2);   // 128 MB

    cast_x_kernel<<<(M_DIM * (size_t)K_DIM / 8) / 256, 256, 0, stream>>>(x, xb);
    dequant_w_kernel<<<(N_DIM * (size_t)K_DIM / 16) / 256, 256, 0, stream>>>(wq, wos, wis, wb);
    gemm_bt_kernel<<<(M_DIM / BM) * (N_DIM / BN), 512, 0, stream>>>(xb, wb, out);
}

// Round 6
// 1309.726 us; speedup vs baseline: 1.4916x; 1.0378x over previous
//
#include <hip/hip_runtime.h>
#include <hip/hip_bf16.h>
#include <stdint.h>
#include <stddef.h>

// ---------------- problem dims (fixed by setup_inputs) ----------------
#define M_DIM 8192
#define K_DIM 4096
#define N_DIM 16384

#define BM 256
#define BN 256
#define BK 64
#define KT (K_DIM / BK)         // 64 K-tiles
#define SLOT_SH (BM * BK)       // 16384 shorts = 32 KB per matrix per slot

typedef __attribute__((ext_vector_type(8))) short bf16x8;  // 8 bf16 = 4 VGPRs
typedef __attribute__((ext_vector_type(4))) float f32x4;
typedef __attribute__((ext_vector_type(4))) int   i32x4;

// fp32 -> bf16, round-to-nearest-even (inputs finite)
static __device__ __forceinline__ short f2bf(float f) {
    union { float f; uint32_t u; } v; v.f = f;
    uint32_t r = v.u + 0x7FFFu + ((v.u >> 16) & 1u);
    return (short)(r >> 16);
}

// FP4 E2M1 decode: low 3 bits magnitude code, bit 3 sign.
static __device__ __forceinline__ float e2m1(int v) {
    int e = (v >> 1) & 3;
    int m = v & 1;
    float mag = (e == 0) ? 0.5f * (float)m
                         : (float)(2 + m) * 0.25f * (float)(1 << e);
    return (v & 8) ? -mag : mag;
}

// async global->LDS, 16 bytes per lane; LDS dest is wave-uniform base + lane*16
static __device__ __forceinline__ void gload16(short* lds, const short* g) {
    __builtin_amdgcn_global_load_lds(
        (const __attribute__((address_space(1))) void*)g,
        (__attribute__((address_space(3))) void*)lds,
        16, 0, 0);
}

// ---------------- kernel 1: x fp32 -> bf16 ----------------
__global__ void cast_x_kernel(const float* __restrict__ x, short* __restrict__ xb) {
    size_t i = (size_t)blockIdx.x * 256 + threadIdx.x;   // one short8 per thread
    const float4* s = reinterpret_cast<const float4*>(x);
    float4 a = s[2 * i];
    float4 b = s[2 * i + 1];
    bf16x8 o;
    o[0] = f2bf(a.x); o[1] = f2bf(a.y); o[2] = f2bf(a.z); o[3] = f2bf(a.w);
    o[4] = f2bf(b.x); o[5] = f2bf(b.y); o[6] = f2bf(b.z); o[7] = f2bf(b.w);
    reinterpret_cast<bf16x8*>(xb)[i] = o;
}

// ---------------- kernel 2: dequant w_q -> bf16 [N, K] ----------------
__global__ void dequant_w_kernel(const int* __restrict__ wq,
                                 const float* __restrict__ wos,
                                 const float* __restrict__ wis,
                                 short* __restrict__ wb) {
    int tid = blockIdx.x * 256 + threadIdx.x;    // N*(K/16) = 4,194,304 total
    int n   = tid >> 8;                          // K/16 = 256 inner blocks per row
    int blk = tid & 255;
    float scale = wis[(n << 8) | blk] * wos[(n << 5) | (blk >> 3)];
    const i32x4* q = reinterpret_cast<const i32x4*>(wq + ((size_t)n << 11) + (blk << 3));
    i32x4 q0 = q[0], q1 = q[1];
    bf16x8 o0, o1;
#pragma unroll
    for (int j = 0; j < 4; ++j) {
        int c = q0[j];
        o0[2 * j]     = f2bf(e2m1(c & 15) * scale);         // even in-feature
        o0[2 * j + 1] = f2bf(e2m1((c >> 4) & 15) * scale);  // odd in-feature
    }
#pragma unroll
    for (int j = 0; j < 4; ++j) {
        int c = q1[j];
        o1[2 * j]     = f2bf(e2m1(c & 15) * scale);
        o1[2 * j + 1] = f2bf(e2m1((c >> 4) & 15) * scale);
    }
    bf16x8* dst = reinterpret_cast<bf16x8*>(wb) + 2 * (size_t)tid;
    dst[0] = o0;
    dst[1] = o1;
}

// ---------------- kernel 3: C[M,N] = A[M,K] * B[N,K]^T, bf16 in / fp32 out --
// 8-phase m201-style template: 256x256 tile, BK=64, 2 LDS slots (128 KB),
// 8 waves (2m x 4n, 128x64 C per wave). Per K-tile: 4 phases of
// {<=8 ds_read_b128 ; stage half-tiles ; barrier ; 16-MFMA cluster ; barrier}.
// Counted vmcnt(4) once per K-tile (never 0 in-loop, T4). setprio around
// MFMA (T5). 8-slot XOR involution swizzle (slot' = chunk ^ (row&7)) applied
// on BOTH the pre-swizzled global source and the ds_read addr (rule #21).
// Race audit: stage writes slot kt+1 (!= read slot kt); that slot's last
// reader finished at kt-1 P4's closing barrier; landing is confirmed by the
// NEXT K-tile's vmcnt(4)+barrier before any read. Wrap stage at kt=63 is
// dead data, race-free.
__global__ __launch_bounds__(512)
void gemm_bt_kernel(const short* __restrict__ A,
                    const short* __restrict__ B,
                    float* __restrict__ C) {
    __shared__ __align__(16) short As[2 * SLOT_SH];   // 64 KB
    __shared__ __align__(16) short Bs[2 * SLOT_SH];   // 64 KB

    // raster: each XCD owns an 8-wide n-stripe, n-fast (R3, FETCH-verified)
    int bid = blockIdx.x;
    int xcd = bid & 7;
    int idx = bid >> 3;          // 0..255
    int im  = idx >> 3;          // 0..31
    int in8 = idx & 7;           // 0..7
    int bm  = im << 8;
    int bn  = ((xcd << 3) + in8) << 8;

    int t    = threadIdx.x;
    int lane = t & 63;
    int w    = t >> 6;           // wave 0..7
    int wm   = w >> 2;           // 0..1
    int wn   = w & 3;            // 0..3
    int fr   = lane & 15;
    int fq   = lane >> 4;
    int wbase = w << 9;          // wave staging base (shorts): w * 512

    // staging: thread t covers row (t>>3) of each 64-row chunk, 16B slot t&7.
    // pre-swizzled global k-chunk = (t&7) ^ (row&7)
    int gcol = (((t & 7) ^ ((t >> 3) & 7)) << 3);        // shorts
    const short* AgB = A + (size_t)(bm + (t >> 3)) * K_DIM + gcol;
    const short* BgB = B + (size_t)(bn + (t >> 3)) * K_DIM + gcol;

    // read-side swizzled slots: frag (kk,fq) needs global chunk kk*4+fq at
    // row ...+fr  ->  stored slot = (kk*4+fq) ^ (fr&7)
    int s0 = fq ^ (fr & 7);      // kk = 0
    int s1 = s0 ^ 4;             // kk = 1
    int aBase = ((wm << 7) + fr) * 8;    // bf16x8 units
    int bBase = ((wn << 6) + fr) * 8;

    f32x4 acc[8][4] = {};

    // stage one 256-row matrix K-tile = 4 chunks of 64 rows (4 gloads/thread)
#define STAGE_A(slot_, kt_)                                                   \
    do {                                                                      \
        const short* _s = AgB + (size_t)(kt_) * BK;                           \
        short* _d = As + (slot_) * SLOT_SH + wbase;                           \
        gload16(_d,         _s);                                              \
        gload16(_d + 4096,  _s + (size_t)64  * K_DIM);                        \
        gload16(_d + 8192,  _s + (size_t)128 * K_DIM);                        \
        gload16(_d + 12288, _s + (size_t)192 * K_DIM);                        \
    } while (0)
#define STAGE_B(slot_, kt_)                                                   \
    do {                                                                      \
        const short* _s = BgB + (size_t)(kt_) * BK;                           \
        short* _d = Bs + (slot_) * SLOT_SH + wbase;                           \
        gload16(_d,         _s);                                              \
        gload16(_d + 4096,  _s + (size_t)64  * K_DIM);                        \
        gload16(_d + 8192,  _s + (size_t)128 * K_DIM);                        \
        gload16(_d + 12288, _s + (size_t)192 * K_DIM);                        \
    } while (0)

    // prologue: stage K-tile 0
    STAGE_A(0, 0);
    STAGE_B(0, 0);

    for (int kt = 0; kt < KT; ++kt) {
        int c     = kt & 1;
        int nslot = c ^ 1;
        int ktn   = (kt + 1) & (KT - 1);   // dead wrap at kt = KT-1
        const bf16x8* Af = reinterpret_cast<const bf16x8*>(As + c * SLOT_SH);
        const bf16x8* Bf = reinterpret_cast<const bf16x8*>(Bs + c * SLOT_SH);

        bf16x8 av[4], bv[4];

        // ---- P1: stage A(kt+1); vmcnt(4); bar; read m0-3/kk0 + B/kk0; MFMA
        STAGE_A(nslot, ktn);
        asm volatile("s_waitcnt vmcnt(4)" ::: "memory");  // kt's 8 loads landed
        __builtin_amdgcn_s_barrier();
        av[0] = Af[aBase + s0];
#pragma unroll
        for (int ni = 0; ni < 4; ++ni) bv[ni] = Bf[bBase + ni * 128 + s0];
#pragma unroll
        for (int mi = 1; mi < 4; ++mi) av[mi] = Af[aBase + mi * 128 + s0];
        __builtin_amdgcn_s_setprio(1);
#pragma unroll
        for (int mi = 0; mi < 4; ++mi)
#pragma unroll
            for (int ni = 0; ni < 4; ++ni)
                acc[mi][ni] = __builtin_amdgcn_mfma_f32_16x16x32_bf16(
                    av[mi], bv[ni], acc[mi][ni], 0, 0, 0);
        __builtin_amdgcn_s_setprio(0);
        __builtin_amdgcn_s_barrier();

        // ---- P2: read m4-7/kk0; stage B(kt+1); bar; MFMA (bv reused)
#pragma unroll
        for (int mi = 0; mi < 4; ++mi) av[mi] = Af[aBase + (mi + 4) * 128 + s0];
        STAGE_B(nslot, ktn);
        __builtin_amdgcn_s_barrier();
        __builtin_amdgcn_s_setprio(1);
#pragma unroll
        for (int mi = 0; mi < 4; ++mi)
#pragma unroll
            for (int ni = 0; ni < 4; ++ni)
                acc[mi + 4][ni] = __builtin_amdgcn_mfma_f32_16x16x32_bf16(
                    av[mi], bv[ni], acc[mi + 4][ni], 0, 0, 0);
        __builtin_amdgcn_s_setprio(0);
        __builtin_amdgcn_s_barrier();

        // ---- P3: read m0-3/kk1 + B/kk1; bar; MFMA
        av[0] = Af[aBase + s1];
#pragma unroll
        for (int ni = 0; ni < 4; ++ni) bv[ni] = Bf[bBase + ni * 128 + s1];
#pragma unroll
        for (int mi = 1; mi < 4; ++mi) av[mi] = Af[aBase + mi * 128 + s1];
        __builtin_amdgcn_s_barrier();
        __builtin_amdgcn_s_setprio(1);
#pragma unroll
        for (int mi = 0; mi < 4; ++mi)
#pragma unroll
            for (int ni = 0; ni < 4; ++ni)
                acc[mi][ni] = __builtin_amdgcn_mfma_f32_16x16x32_bf16(
                    av[mi], bv[ni], acc[mi][ni], 0, 0, 0);
        __builtin_amdgcn_s_setprio(0);
        __builtin_amdgcn_s_barrier();

        // ---- P4: read m4-7/kk1; bar; MFMA
#pragma unroll
        for (int mi = 0; mi < 4; ++mi) av[mi] = Af[aBase + (mi + 4) * 128 + s1];
        __builtin_amdgcn_s_barrier();
        __builtin_amdgcn_s_setprio(1);
#pragma unroll
        for (int mi = 0; mi < 4; ++mi)
#pragma unroll
            for (int ni = 0; ni < 4; ++ni)
                acc[mi + 4][ni] = __builtin_amdgcn_mfma_f32_16x16x32_bf16(
                    av[mi], bv[ni], acc[mi + 4][ni], 0, 0, 0);
        __builtin_amdgcn_s_setprio(0);
        __builtin_amdgcn_s_barrier();
    }
#undef STAGE_A
#undef STAGE_B

    // epilogue: C/D layout col = lane&15, row = (lane>>4)*4 + reg
#pragma unroll
    for (int mi = 0; mi < 8; ++mi) {
#pragma unroll
        for (int j = 0; j < 4; ++j) {
            size_t row = (size_t)(bm + (wm << 7) + mi * 16 + fq * 4 + j);
            float* Crow = C + row * N_DIM + (bn + (wn << 6) + fr);
#pragma unroll
            for (int ni = 0; ni < 4; ++ni)
                Crow[ni * 16] = acc[mi][ni][j];
        }
    }
}

// ---------------- launch ----------------
extern "C" void kernel_launch(void* const* d_in, const int* in_sizes, int n_in,
                              void* d_out, int out_size, void* d_ws, size_t ws_size,
                              hipStream_t stream) {
    const float* x   = (const float*)d_in[0];
    const int*   wq  = (const int*)d_in[1];
    const float* wos = (const float*)d_in[2];
    const float* wis = (const float*)d_in[3];
    float* out = (float*)d_out;

    short* xb = (short*)d_ws;                                        // 64 MB
    short* wb = (short*)((char*)d_ws + (size_t)M_DIM * K_DIM * 2);   // 128 MB

    cast_x_kernel<<<(M_DIM * (size_t)K_DIM / 8) / 256, 256, 0, stream>>>(x, xb);
    dequant_w_kernel<<<(N_DIM * (size_t)K_DIM / 16) / 256, 256, 0, stream>>>(wq, wos, wis, wb);
    gemm_bt_kernel<<<(M_DIM / BM) * (N_DIM / BN), 512, 0, stream>>>(xb, wb, out);
}

// Round 7
// 1226.179 us; speedup vs baseline: 1.5932x; 1.0681x over previous
//
#include <hip/hip_runtime.h>
#include <hip/hip_bf16.h>
#include <stdint.h>
#include <stddef.h>

// ---------------- problem dims (fixed by setup_inputs) ----------------
#define M_DIM 8192
#define K_DIM 4096
#define N_DIM 16384

#define BM 256
#define BN 256
#define BK 64
#define KT (K_DIM / BK)         // 64 K-tiles
#define SLOT_SH (BM * BK)       // 16384 shorts = 32 KB per matrix per slot

typedef __attribute__((ext_vector_type(8))) short bf16x8;  // 8 bf16 = 4 VGPRs
typedef __attribute__((ext_vector_type(4))) float f32x4;
typedef __attribute__((ext_vector_type(4))) int   i32x4;

// fp32 -> bf16, round-to-nearest-even (inputs finite)
static __device__ __forceinline__ short f2bf(float f) {
    union { float f; uint32_t u; } v; v.f = f;
    uint32_t r = v.u + 0x7FFFu + ((v.u >> 16) & 1u);
    return (short)(r >> 16);
}

// FP4 E2M1 decode: low 3 bits magnitude code, bit 3 sign.
static __device__ __forceinline__ float e2m1(int v) {
    int e = (v >> 1) & 3;
    int m = v & 1;
    float mag = (e == 0) ? 0.5f * (float)m
                         : (float)(2 + m) * 0.25f * (float)(1 << e);
    return (v & 8) ? -mag : mag;
}

// async global->LDS, 16 bytes per lane; LDS dest is wave-uniform base + lane*16
static __device__ __forceinline__ void gload16(short* lds, const short* g) {
    __builtin_amdgcn_global_load_lds(
        (const __attribute__((address_space(1))) void*)g,
        (__attribute__((address_space(3))) void*)lds,
        16, 0, 0);
}

// ---------------- kernel 1: x fp32 -> bf16 ----------------
__global__ void cast_x_kernel(const float* __restrict__ x, short* __restrict__ xb) {
    size_t i = (size_t)blockIdx.x * 256 + threadIdx.x;   // one short8 per thread
    const float4* s = reinterpret_cast<const float4*>(x);
    float4 a = s[2 * i];
    float4 b = s[2 * i + 1];
    bf16x8 o;
    o[0] = f2bf(a.x); o[1] = f2bf(a.y); o[2] = f2bf(a.z); o[3] = f2bf(a.w);
    o[4] = f2bf(b.x); o[5] = f2bf(b.y); o[6] = f2bf(b.z); o[7] = f2bf(b.w);
    reinterpret_cast<bf16x8*>(xb)[i] = o;
}

// ---------------- kernel 2: dequant w_q -> bf16 [N, K] ----------------
__global__ void dequant_w_kernel(const int* __restrict__ wq,
                                 const float* __restrict__ wos,
                                 const float* __restrict__ wis,
                                 short* __restrict__ wb) {
    int tid = blockIdx.x * 256 + threadIdx.x;    // N*(K/16) = 4,194,304 total
    int n   = tid >> 8;                          // K/16 = 256 inner blocks per row
    int blk = tid & 255;
    float scale = wis[(n << 8) | blk] * wos[(n << 5) | (blk >> 3)];
    const i32x4* q = reinterpret_cast<const i32x4*>(wq + ((size_t)n << 11) + (blk << 3));
    i32x4 q0 = q[0], q1 = q[1];
    bf16x8 o0, o1;
#pragma unroll
    for (int j = 0; j < 4; ++j) {
        int c = q0[j];
        o0[2 * j]     = f2bf(e2m1(c & 15) * scale);         // even in-feature
        o0[2 * j + 1] = f2bf(e2m1((c >> 4) & 15) * scale);  // odd in-feature
    }
#pragma unroll
    for (int j = 0; j < 4; ++j) {
        int c = q1[j];
        o1[2 * j]     = f2bf(e2m1(c & 15) * scale);
        o1[2 * j + 1] = f2bf(e2m1((c >> 4) & 15) * scale);
    }
    bf16x8* dst = reinterpret_cast<bf16x8*>(wb) + 2 * (size_t)tid;
    dst[0] = o0;
    dst[1] = o1;
}

// ---------------- kernel 3: C[M,N] = A[M,K] * B[N,K]^T, bf16 in / fp32 out --
// m201 8-phase template, faithful ordering (R7 fix): per phase the ds_reads
// and staging are issued BEFORE the opening barrier; the MFMA cluster runs
// after {barrier; lgkmcnt(0); sched_barrier(0)} so the DS drain overlaps
// barrier skew + the previous phase's matrix-pipe tail instead of sitting on
// the critical path (R6 measured 6120 cyc/K-tile vs template's ~3300; the
// read-after-barrier placement was the 1.85x).
// Counted-vmem discipline: the only vmem wait is in ph3 (once per K-tile),
// when exactly the 8 tile-(kt+1) loads are outstanding, issued >=2 phases
// earlier. setprio(1) around MFMA (T5). Both-sides XOR slot swizzle
// (verified conflict-free in R4-R6: SQ_LDS_BANK_CONFLICT == 0).
// Race audit: stage writes slot kt+1 (!= read slot kt); that slot's last
// reader finished at kt-1 ph3's closing barrier; landing is confirmed by
// ph3's vmcnt + closing barrier before the next ph0 read.
__global__ __launch_bounds__(512)
void gemm_bt_kernel(const short* __restrict__ A,
                    const short* __restrict__ B,
                    float* __restrict__ C) {
    __shared__ __align__(16) short As[2 * SLOT_SH];   // 64 KB
    __shared__ __align__(16) short Bs[2 * SLOT_SH];   // 64 KB

    // raster: each XCD owns an 8-wide n-stripe, n-fast (R3, FETCH-verified)
    int bid = blockIdx.x;
    int xcd = bid & 7;
    int idx = bid >> 3;          // 0..255
    int im  = idx >> 3;          // 0..31
    int in8 = idx & 7;           // 0..7
    int bm  = im << 8;
    int bn  = ((xcd << 3) + in8) << 8;

    int t    = threadIdx.x;
    int lane = t & 63;
    int w    = t >> 6;           // wave 0..7
    int wm   = w >> 2;           // 0..1
    int wn   = w & 3;            // 0..3
    int fr   = lane & 15;
    int fq   = lane >> 4;
    int wbase = w << 9;          // wave staging base (shorts): w * 512

    // staging: thread t covers row (t>>3) of each 64-row chunk, 16B slot t&7.
    // pre-swizzled global k-chunk = (t&7) ^ (row&7)
    int gcol = (((t & 7) ^ ((t >> 3) & 7)) << 3);        // shorts
    const short* AgB = A + (size_t)(bm + (t >> 3)) * K_DIM + gcol;
    const short* BgB = B + (size_t)(bn + (t >> 3)) * K_DIM + gcol;

    // read-side swizzled slots: frag (kk,fq) needs global chunk kk*4+fq at
    // row ...+fr  ->  stored slot = (kk*4+fq) ^ (fr&7)
    int s0 = fq ^ (fr & 7);      // kk = 0
    int s1 = s0 ^ 4;             // kk = 1
    int aBase = ((wm << 7) + fr) * 8;    // bf16x8 units
    int bBase = ((wn << 6) + fr) * 8;

    f32x4 acc[8][4] = {};

    // stage one 256-row matrix K-tile = 4 chunks of 64 rows (4 gloads/thread)
#define STAGE_A(slot_, kt_)                                                   \
    do {                                                                      \
        const short* _s = AgB + (size_t)(kt_) * BK;                           \
        short* _d = As + (slot_) * SLOT_SH + wbase;                           \
        gload16(_d,         _s);                                              \
        gload16(_d + 4096,  _s + (size_t)64  * K_DIM);                        \
        gload16(_d + 8192,  _s + (size_t)128 * K_DIM);                        \
        gload16(_d + 12288, _s + (size_t)192 * K_DIM);                        \
    } while (0)
#define STAGE_B(slot_, kt_)                                                   \
    do {                                                                      \
        const short* _s = BgB + (size_t)(kt_) * BK;                           \
        short* _d = Bs + (slot_) * SLOT_SH + wbase;                           \
        gload16(_d,         _s);                                              \
        gload16(_d + 4096,  _s + (size_t)64  * K_DIM);                        \
        gload16(_d + 8192,  _s + (size_t)128 * K_DIM);                        \
        gload16(_d + 12288, _s + (size_t)192 * K_DIM);                        \
    } while (0)

// phase boundary: pin reads/stage above, then barrier, then drain LDS and
// pin again so MFMA can't hoist past the wait (rule #18)
#define PHASE_GATE()                                                          \
    do {                                                                      \
        __builtin_amdgcn_sched_barrier(0);                                    \
        __builtin_amdgcn_s_barrier();                                         \
        asm volatile("s_waitcnt lgkmcnt(0)" ::: "memory");                    \
        __builtin_amdgcn_sched_barrier(0);                                    \
    } while (0)

    // prologue: stage K-tile 0, drain, sync
    STAGE_A(0, 0);
    STAGE_B(0, 0);
    asm volatile("s_waitcnt vmcnt(0)" ::: "memory");
    __builtin_amdgcn_s_barrier();

    for (int kt = 0; kt < KT; ++kt) {
        int c     = kt & 1;
        int nslot = c ^ 1;
        int ktn   = (kt + 1) & (KT - 1);   // dead wrap at kt = KT-1
        const bf16x8* Af = reinterpret_cast<const bf16x8*>(As + c * SLOT_SH);
        const bf16x8* Bf = reinterpret_cast<const bf16x8*>(Bs + c * SLOT_SH);

        bf16x8 av[4], aw[4], bv[4];

        // ---- ph0: reads m0-3/kk0 + B/kk0; stage A(kt+1); gate; MFMA Q0
#pragma unroll
        for (int ni = 0; ni < 4; ++ni) bv[ni] = Bf[bBase + ni * 128 + s0];
#pragma unroll
        for (int mi = 0; mi < 4; ++mi) av[mi] = Af[aBase + mi * 128 + s0];
        STAGE_A(nslot, ktn);
        PHASE_GATE();
        __builtin_amdgcn_s_setprio(1);
#pragma unroll
        for (int mi = 0; mi < 4; ++mi)
#pragma unroll
            for (int ni = 0; ni < 4; ++ni)
                acc[mi][ni] = __builtin_amdgcn_mfma_f32_16x16x32_bf16(
                    av[mi], bv[ni], acc[mi][ni], 0, 0, 0);
        __builtin_amdgcn_s_setprio(0);
        __builtin_amdgcn_s_barrier();

        // ---- ph1: reads m4-7/kk0; stage B(kt+1); gate; MFMA Q1 (bv reused)
#pragma unroll
        for (int mi = 0; mi < 4; ++mi) aw[mi] = Af[aBase + (mi + 4) * 128 + s0];
        STAGE_B(nslot, ktn);
        PHASE_GATE();
        __builtin_amdgcn_s_setprio(1);
#pragma unroll
        for (int mi = 0; mi < 4; ++mi)
#pragma unroll
            for (int ni = 0; ni < 4; ++ni)
                acc[mi + 4][ni] = __builtin_amdgcn_mfma_f32_16x16x32_bf16(
                    aw[mi], bv[ni], acc[mi + 4][ni], 0, 0, 0);
        __builtin_amdgcn_s_setprio(0);
        __builtin_amdgcn_s_barrier();

        // ---- ph2: reads m0-3/kk1 + B/kk1; gate; MFMA Q0
#pragma unroll
        for (int ni = 0; ni < 4; ++ni) bv[ni] = Bf[bBase + ni * 128 + s1];
#pragma unroll
        for (int mi = 0; mi < 4; ++mi) av[mi] = Af[aBase + mi * 128 + s1];
        PHASE_GATE();
        __builtin_amdgcn_s_setprio(1);
#pragma unroll
        for (int mi = 0; mi < 4; ++mi)
#pragma unroll
            for (int ni = 0; ni < 4; ++ni)
                acc[mi][ni] = __builtin_amdgcn_mfma_f32_16x16x32_bf16(
                    av[mi], bv[ni], acc[mi][ni], 0, 0, 0);
        __builtin_amdgcn_s_setprio(0);
        __builtin_amdgcn_s_barrier();

        // ---- ph3: reads m4-7/kk1; gate; MFMA Q1; vmem wait; closing barrier
#pragma unroll
        for (int mi = 0; mi < 4; ++mi) aw[mi] = Af[aBase + (mi + 4) * 128 + s1];
        PHASE_GATE();
        __builtin_amdgcn_s_setprio(1);
#pragma unroll
        for (int mi = 0; mi < 4; ++mi)
#pragma unroll
            for (int ni = 0; ni < 4; ++ni)
                acc[mi + 4][ni] = __builtin_amdgcn_mfma_f32_16x16x32_bf16(
                    aw[mi], bv[ni], acc[mi + 4][ni], 0, 0, 0);
        __builtin_amdgcn_s_setprio(0);
        // tile kt+1's 8 loads (the only outstanding vmem, issued >=2 phases
        // ago) must land before the next ph0's reads; per-wave wait here,
        // cross-wave visibility via the closing barrier.
        asm volatile("s_waitcnt vmcnt(0)" ::: "memory");
        __builtin_amdgcn_s_barrier();
    }
#undef PHASE_GATE
#undef STAGE_A
#undef STAGE_B

    // epilogue: C/D layout col = lane&15, row = (lane>>4)*4 + reg
#pragma unroll
    for (int mi = 0; mi < 8; ++mi) {
#pragma unroll
        for (int j = 0; j < 4; ++j) {
            size_t row = (size_t)(bm + (wm << 7) + mi * 16 + fq * 4 + j);
            float* Crow = C + row * N_DIM + (bn + (wn << 6) + fr);
#pragma unroll
            for (int ni = 0; ni < 4; ++ni)
                Crow[ni * 16] = acc[mi][ni][j];
        }
    }
}

// ---------------- launch ----------------
extern "C" void kernel_launch(void* const* d_in, const int* in_sizes, int n_in,
                              void* d_out, int out_size, void* d_ws, size_t ws_size,
                              hipStream_t stream) {
    const float* x   = (const float*)d_in[0];
    const int*   wq  = (const int*)d_in[1];
    const float* wos = (const float*)d_in[2];
    const float* wis = (const float*)d_in[3];
    float* out = (float*)d_out;

    short* xb = (short*)d_ws;                                        // 64 MB
    short* wb = (short*)((char*)d_ws + (size_t)M_DIM * K_DIM * 2);   // 128 MB

    cast_x_kernel<<<(M_DIM * (size_t)K_DIM / 8) / 256, 256, 0, stream>>>(x, xb);
    dequant_w_kernel<<<(N_DIM * (size_t)K_DIM / 16) / 256, 256, 0, stream>>>(wq, wos, wis, wb);
    gemm_bt_kernel<<<(M_DIM / BM) * (N_DIM / BN), 512, 0, stream>>>(xb, wb, out);
}